// Round 1
// baseline (157.160 us; speedup 1.0000x reference)
//
#include <hip/hip_runtime.h>
#include <hip/hip_fp16.h>

#define LN_EPS 1e-5f

typedef _Float16 f16x2 __attribute__((ext_vector_type(2)));
typedef _Float16 f16x8 __attribute__((ext_vector_type(8)));

__device__ __forceinline__ void pk_atomic_add(_Float16* p, float v0, float v1) {
  f16x2 v;
  v.x = (_Float16)v0;
  v.y = (_Float16)v1;
#if __has_builtin(__builtin_amdgcn_flat_atomic_fadd_v2f16)
  __builtin_amdgcn_flat_atomic_fadd_v2f16((f16x2*)p, v);
#else
  unsafeAtomicAdd((__half2*)p, *(__half2*)&v);
#endif
}

// ---------------------------------------------------------------------------
// Algebra: per-edge contribution to the (pre-mean) node feature is
//   contrib[col] = sum_h a_h (rel . M_h[col] + cv_h[col])
// linear in f = (a0,a1,a2, rx,ry,rz, a_h*rel_i for h<3, 1)  [16 dims]
// (sum_h a_h = 1 eliminates head 3). scatter-mean(contrib) = scatter-mean(f) @ T.
// f[15] = 1 doubles as the count. f accumulated in f16 via packed atomics.
//
// This version folds the old single-block precompute dispatch away:
//  - coef (40 floats) + int64-layout flag: recomputed per edge-block into LDS
//    (weights are ~4 KB, L2-hot; aggregate cost ~2 us, overlapped).
//  - T (512 floats): computed by edge-block 0 into ws, concurrent with all
//    other edge blocks; node_kernel reads it after the kernel boundary.
//
// ws layout: [0, N*16) _Float16 f-sum accumulators, then T (512 floats).
// ---------------------------------------------------------------------------

__device__ __forceinline__ void sel_comp(int comp, int& pa, int& pr) {
  if (comp < 3)       { pa = comp;           pr = 3; }
  else if (comp < 6)  { pa = 3;              pr = comp - 3; }
  else if (comp < 15) { pa = (comp - 6) / 3; pr = (comp - 6) % 3; }
  else                { pa = 3;              pr = 3; }
}

__global__ __launch_bounds__(256) void edge_kernel(
    const float* __restrict__ pos, const int* __restrict__ ei, int E,
    const float* __restrict__ Wq, const float* __restrict__ bq,
    const float* __restrict__ Wk, const float* __restrict__ bk,
    const float* __restrict__ Wv, const float* __restrict__ bv,
    const float* __restrict__ Wout, float* __restrict__ T,
    _Float16* __restrict__ fsums) {
  __shared__ float scoef[40];
  __shared__ int sflag;
  __shared__ float sM[4][3][32];
  __shared__ float sCv[4][32];
  const int t = threadIdx.x;
  const float scale = 0.17677669529663687f;  // 1/sqrt(32)

  if (t == 0) {
    // int64 edge_index layout probe: odd 32-bit words of 8 indices in
    // [0,1e5) are all zero iff the buffer is little-endian int64.
    int all_zero = 1;
#pragma unroll
    for (int i = 0; i < 8; ++i) all_zero &= (ei[2 * i + 1] == 0);
    sflag = all_zero;
  }

  if (t < 40) {
    const int h = t / 10, j = t % 10;
    float acc = 0.f;
    for (int d = 0; d < 32; ++d) {
      const int idx = h * 32 + d;
      float q0 = Wq[idx], q1 = Wq[128 + idx], q2 = Wq[256 + idx];
      float k0 = Wk[idx], k1 = Wk[128 + idx], k2 = Wk[256 + idx];
      float bqv = bq[idx], bkv = bk[idx];
      float v;
      switch (j) {
        case 0: v = q0 * k0; break;
        case 1: v = q1 * k1; break;
        case 2: v = q2 * k2; break;
        case 3: v = q0 * k1 + q1 * k0; break;
        case 4: v = q0 * k2 + q2 * k0; break;
        case 5: v = q1 * k2 + q2 * k1; break;
        case 6: v = q0 * bkv + k0 * bqv; break;
        case 7: v = q1 * bkv + k1 * bqv; break;
        case 8: v = q2 * bkv + k2 * bqv; break;
        default: v = bqv * bkv; break;
      }
      acc += v;
    }
    scoef[t] = acc * scale;
  }

  if (blockIdx.x == 0 && t < 128) {
    const int h = t >> 5, o = t & 31;
    float m0 = 0, m1 = 0, m2 = 0, cv = 0;
    for (int d = 0; d < 32; ++d) {
      const int j = h * 32 + d;
      const float w = Wout[j * 32 + o];
      m0 += Wv[j] * w;
      m1 += Wv[128 + j] * w;
      m2 += Wv[256 + j] * w;
      cv += bv[j] * w;
    }
    sM[h][0][o] = m0;
    sM[h][1][o] = m1;
    sM[h][2][o] = m2;
    sCv[h][o] = cv;
  }

  __syncthreads();

  if (blockIdx.x == 0) {
    for (int idx = t; idx < 512; idx += 256) {
      const int j = idx >> 5, col = idx & 31;
      float v;
      if (j < 3)        v = sCv[j][col] - sCv[3][col];
      else if (j < 6)   v = sM[3][j - 3][col];
      else if (j < 15)  { const int h = (j - 6) / 3, i = (j - 6) % 3; v = sM[h][i][col] - sM[3][i][col]; }
      else              v = sCv[3][col];
      T[idx] = v;
    }
  }

  const int lane = t & 31;
  const int group = (blockIdx.x * blockDim.x + t) >> 5;
  const int base = group * 32;
  if (base >= E) return;

  const int i64 = sflag;
  const int valid_n = min(32, E - base);
  const int e = base + lane;

  int c = 0;
  float rx = 0, ry = 0, rz = 0, a0 = 0, a1 = 0, a2 = 0;
  if (lane < valid_n) {
    int r, cc;
    if (i64) {
      const int2 pr = ((const int2*)ei)[(size_t)e];
      const int2 pc = ((const int2*)ei)[(size_t)E + (size_t)e];
      r = pr.x;
      cc = pc.x;
    } else {
      r = ei[e];
      cc = ei[(size_t)E + e];
    }
    c = cc;
    rx = pos[r * 3 + 0] - pos[cc * 3 + 0];
    ry = pos[r * 3 + 1] - pos[cc * 3 + 1];
    rz = pos[r * 3 + 2] - pos[cc * 3 + 2];
    float s[4];
#pragma unroll
    for (int h = 0; h < 4; ++h) {
      const float* cf = scoef + h * 10;
      s[h] = cf[9] + rx * cf[6] + ry * cf[7] + rz * cf[8] + rx * rx * cf[0] +
             ry * ry * cf[1] + rz * rz * cf[2] + rx * ry * cf[3] +
             rx * rz * cf[4] + ry * rz * cf[5];
    }
    float mx = fmaxf(fmaxf(s[0], s[1]), fmaxf(s[2], s[3]));
    float e0 = __expf(s[0] - mx), e1 = __expf(s[1] - mx);
    float e2 = __expf(s[2] - mx), e3 = __expf(s[3] - mx);
    float inv = 1.0f / (e0 + e1 + e2 + e3);
    a0 = e0 * inv; a1 = e1 * inv; a2 = e2 * inv;  // a3 never needed
  }

  // 8 half2 slots per edge; 32 lanes handle 4 edges per iteration so one
  // wave-atomic touches few cache lines (8 lanes cover one edge's 32 B).
  const int pair = lane & 7;   // half2 slot: comps (2*pair, 2*pair+1)
  const int sub  = lane >> 3;  // which of the 4 in-flight edges
  int pa0, pr0, pa1, pr1;
  sel_comp(2 * pair, pa0, pr0);
  sel_comp(2 * pair + 1, pa1, pr1);

  for (int t2 = 0; t2 < valid_n; t2 += 4) {
    const int src = t2 + sub;
    float tx = __shfl(rx, src, 32);
    float ty = __shfl(ry, src, 32);
    float tz = __shfl(rz, src, 32);
    float b0 = __shfl(a0, src, 32);
    float b1 = __shfl(a1, src, 32);
    float b2 = __shfl(a2, src, 32);
    int   ct = __shfl(c,  src, 32);
    float A0 = (pa0 == 0) ? b0 : (pa0 == 1) ? b1 : (pa0 == 2) ? b2 : 1.0f;
    float R0 = (pr0 == 0) ? tx : (pr0 == 1) ? ty : (pr0 == 2) ? tz : 1.0f;
    float A1 = (pa1 == 0) ? b0 : (pa1 == 1) ? b1 : (pa1 == 2) ? b2 : 1.0f;
    float R1 = (pr1 == 0) ? tx : (pr1 == 1) ? ty : (pr1 == 2) ? tz : 1.0f;
    if (src < valid_n)
      pk_atomic_add(fsums + (size_t)ct * 16 + 2 * pair, A0 * R0, A1 * R1);
  }
}

__global__ __launch_bounds__(256) void node_kernel(
    const _Float16* __restrict__ fsums, const float* __restrict__ T,
    const float* __restrict__ bout, const float* __restrict__ gamma,
    const float* __restrict__ beta, float* __restrict__ out, int N) {
  const int tid = blockIdx.x * blockDim.x + threadIdx.x;
  const int node = tid >> 5;
  const int col = tid & 31;
  if (node >= N) return;

  // All 32 lanes of a node read the same 32 B (two dwordx4 broadcast loads)
  // instead of 16 ds_bpermute broadcasts.
  const f16x8* fp = (const f16x8*)(fsums + (size_t)node * 16);
  const f16x8 va = fp[0];
  const f16x8 vb = fp[1];
  float f[16];
#pragma unroll
  for (int j = 0; j < 8; ++j) {
    f[j] = (float)va[j];
    f[8 + j] = (float)vb[j];
  }
  const float invc = 1.0f / fmaxf(f[15], 1.0f);

  float acc = 0.f;
#pragma unroll
  for (int j = 0; j < 16; ++j) acc = fmaf(f[j], T[j * 32 + col], acc);
  acc = fmaf(acc, invc, bout[col]);

  float sx = acc, sx2 = acc * acc;
#pragma unroll
  for (int off = 16; off >= 1; off >>= 1) {
    sx += __shfl_xor(sx, off);
    sx2 += __shfl_xor(sx2, off);
  }
  const float mu = sx * (1.0f / 32.0f);
  const float var = sx2 * (1.0f / 32.0f) - mu * mu;
  const float inv = rsqrtf(var + LN_EPS);
  const float y = (acc - mu) * inv * gamma[col] + beta[col];
  const float o = y * (1.0f / (1.0f + __expf(-y)));  // SiLU
  out[(size_t)node * 32 + col] = o;
}

extern "C" void kernel_launch(void* const* d_in, const int* in_sizes, int n_in,
                              void* d_out, int out_size, void* d_ws, size_t ws_size,
                              hipStream_t stream) {
  const float* pos  = (const float*)d_in[0];
  const int*   ei   = (const int*)d_in[1];
  const float* Wq   = (const float*)d_in[2];
  const float* bq   = (const float*)d_in[3];
  const float* Wk   = (const float*)d_in[4];
  const float* bk   = (const float*)d_in[5];
  const float* Wv   = (const float*)d_in[6];
  const float* bv   = (const float*)d_in[7];
  const float* Wout = (const float*)d_in[8];
  const float* bout = (const float*)d_in[9];
  const float* gam  = (const float*)d_in[10];
  const float* bet  = (const float*)d_in[11];

  const int N = in_sizes[0] / 3;
  const int E = in_sizes[1] / 2;

  _Float16* fsums = (_Float16*)d_ws;                       // N*16 halves
  float* T = (float*)((char*)d_ws + (size_t)N * 32);       // 512 floats

  hipMemsetAsync(d_ws, 0, (size_t)N * 32, stream);

  const int edge_blocks = (E + 255) / 256;  // 8 groups of 32 edges per block
  edge_kernel<<<edge_blocks, 256, 0, stream>>>(pos, ei, E, Wq, bq, Wk, bk, Wv,
                                               bv, Wout, T, fsums);

  const int node_blocks = (int)(((size_t)N * 32 + 255) / 256);
  node_kernel<<<node_blocks, 256, 0, stream>>>(fsums, T, bout, gam, bet,
                                               (float*)d_out, N);

  (void)n_in; (void)out_size; (void)ws_size;
}

// Round 2
// 147.127 us; speedup vs baseline: 1.0682x; 1.0682x over previous
//
#include <hip/hip_runtime.h>
#include <hip/hip_fp16.h>

#define LN_EPS 1e-5f

typedef _Float16 f16x2 __attribute__((ext_vector_type(2)));
typedef _Float16 f16x8 __attribute__((ext_vector_type(8)));

__device__ __forceinline__ void pk_atomic_add(_Float16* p, float v0, float v1) {
  f16x2 v;
  v.x = (_Float16)v0;
  v.y = (_Float16)v1;
#if __has_builtin(__builtin_amdgcn_flat_atomic_fadd_v2f16)
  __builtin_amdgcn_flat_atomic_fadd_v2f16((f16x2*)p, v);
#else
  unsafeAtomicAdd((__half2*)p, *(__half2*)&v);
#endif
}

// ---------------------------------------------------------------------------
// Algebra: per-edge contribution to the (pre-mean) node feature is
//   contrib[col] = sum_h a_h (rel . M_h[col] + cv_h[col])
// linear in f = (a0,a1,a2, rx,ry,rz, a_h*rel_i for h<3, 1)  [16 dims]
// (sum_h a_h = 1 eliminates head 3). scatter-mean(contrib) = scatter-mean(f) @ T.
// f[15] = 1 doubles as the count. f accumulated in f16 via packed atomics.
//
// Round-2 structure: no separate precompute dispatch, but the per-block coef
// recompute now goes through LDS:
//  - stage Wq/Wk/bq/bk (4 KB) with coalesced full-block loads, THEN the
//    40-thread coef loop reads LDS only (round-1's version looped on global
//    loads -> +26 us on the edge kernel).
//  - int64-layout flag via per-wave ballot (no barrier), so each lane issues
//    its ei/pos gathers at kernel entry, overlapped with the LDS phases.
//  - block 0 computes T with threads 128..255 (parallel with coef threads).
//
// ws layout: [0, N*16) _Float16 f-sum accumulators, then T (512 floats).
// ---------------------------------------------------------------------------

__device__ __forceinline__ void sel_comp(int comp, int& pa, int& pr) {
  if (comp < 3)       { pa = comp;           pr = 3; }
  else if (comp < 6)  { pa = 3;              pr = comp - 3; }
  else if (comp < 15) { pa = (comp - 6) / 3; pr = (comp - 6) % 3; }
  else                { pa = 3;              pr = 3; }
}

__global__ __launch_bounds__(256) void edge_kernel(
    const float* __restrict__ pos, const int* __restrict__ ei, int E,
    const float* __restrict__ Wq, const float* __restrict__ bq,
    const float* __restrict__ Wk, const float* __restrict__ bk,
    const float* __restrict__ Wv, const float* __restrict__ bv,
    const float* __restrict__ Wout, float* __restrict__ T,
    _Float16* __restrict__ fsums) {
  __shared__ float sW[1024];   // Wq[384] Wk[384] bq[128] bk[128]
  __shared__ float scoef[40];
  __shared__ float sM[4][3][32];
  __shared__ float sCv[4][32];

  const int t = threadIdx.x;
  const int lane64 = t & 63;
  const float scale = 0.17677669529663687f;  // 1/sqrt(32)

  // --- int64 layout probe, wave-local (no barrier): odd 32-bit words of the
  // first 8 indices are all zero iff buffer is little-endian int64.
  bool pz = true;
  if (lane64 < 8) pz = (ei[2 * lane64 + 1] == 0);
  const unsigned long long bz = __ballot(pz);
  const int i64 = (int)__builtin_amdgcn_readfirstlane(bz == ~0ull ? 1 : 0);

  // --- issue own-edge gathers immediately; they overlap the LDS phases.
  const int lane = t & 31;
  const int group = (blockIdx.x * blockDim.x + t) >> 5;
  const int base = group * 32;
  const int valid_n = (base < E) ? min(32, E - base) : 0;
  const int e = base + lane;

  int c = 0;
  float px0 = 0, px1 = 0, px2 = 0, pc0 = 0, pc1 = 0, pc2 = 0;
  if (lane < valid_n) {
    int r;
    if (i64) {
      r = ((const int2*)ei)[(size_t)e].x;
      c = ((const int2*)ei)[(size_t)E + (size_t)e].x;
    } else {
      r = ei[e];
      c = ei[(size_t)E + e];
    }
    px0 = pos[r * 3 + 0]; px1 = pos[r * 3 + 1]; px2 = pos[r * 3 + 2];
    pc0 = pos[c * 3 + 0]; pc1 = pos[c * 3 + 1]; pc2 = pos[c * 3 + 2];
  }

  // --- stage Wq/Wk/bq/bk to LDS (coalesced, whole block)
  for (int i = t; i < 384; i += 256) {
    sW[i] = Wq[i];
    sW[384 + i] = Wk[i];
  }
  if (t < 128) {
    sW[768 + t] = bq[t];
    sW[896 + t] = bk[t];
  }
  __syncthreads();

  // --- coef from LDS (threads 0..39)
  if (t < 40) {
    const int h = t / 10, j = t % 10;
    float acc = 0.f;
#pragma unroll 4
    for (int d = 0; d < 32; ++d) {
      const int idx = h * 32 + d;
      float q0 = sW[idx], q1 = sW[128 + idx], q2 = sW[256 + idx];
      float k0 = sW[384 + idx], k1 = sW[512 + idx], k2 = sW[640 + idx];
      float bqv = sW[768 + idx], bkv = sW[896 + idx];
      float v;
      switch (j) {
        case 0: v = q0 * k0; break;
        case 1: v = q1 * k1; break;
        case 2: v = q2 * k2; break;
        case 3: v = q0 * k1 + q1 * k0; break;
        case 4: v = q0 * k2 + q2 * k0; break;
        case 5: v = q1 * k2 + q2 * k1; break;
        case 6: v = q0 * bkv + k0 * bqv; break;
        case 7: v = q1 * bkv + k1 * bqv; break;
        case 8: v = q2 * bkv + k2 * bqv; break;
        default: v = bqv * bkv; break;
      }
      acc += v;
    }
    scoef[t] = acc * scale;
  }

  // --- block 0 only: T factors, on threads 128..255 (parallel with coef)
  if (blockIdx.x == 0 && t >= 128) {
    const int h = (t - 128) >> 5, o = t & 31;
    float m0 = 0, m1 = 0, m2 = 0, cv = 0;
    for (int d = 0; d < 32; ++d) {
      const int j = h * 32 + d;
      const float w = Wout[j * 32 + o];
      m0 += Wv[j] * w;
      m1 += Wv[128 + j] * w;
      m2 += Wv[256 + j] * w;
      cv += bv[j] * w;
    }
    sM[h][0][o] = m0;
    sM[h][1][o] = m1;
    sM[h][2][o] = m2;
    sCv[h][o] = cv;
  }
  __syncthreads();

  if (blockIdx.x == 0) {
    for (int idx = t; idx < 512; idx += 256) {
      const int j = idx >> 5, col = idx & 31;
      float v;
      if (j < 3)        v = sCv[j][col] - sCv[3][col];
      else if (j < 6)   v = sM[3][j - 3][col];
      else if (j < 15)  { const int h = (j - 6) / 3, i = (j - 6) % 3; v = sM[h][i][col] - sM[3][i][col]; }
      else              v = sCv[3][col];
      T[idx] = v;
    }
  }

  if (valid_n == 0) return;

  float rx = 0, ry = 0, rz = 0, a0 = 0, a1 = 0, a2 = 0;
  if (lane < valid_n) {
    rx = px0 - pc0;
    ry = px1 - pc1;
    rz = px2 - pc2;
    float s[4];
#pragma unroll
    for (int h = 0; h < 4; ++h) {
      const float* cf = scoef + h * 10;
      s[h] = cf[9] + rx * cf[6] + ry * cf[7] + rz * cf[8] + rx * rx * cf[0] +
             ry * ry * cf[1] + rz * rz * cf[2] + rx * ry * cf[3] +
             rx * rz * cf[4] + ry * rz * cf[5];
    }
    float mx = fmaxf(fmaxf(s[0], s[1]), fmaxf(s[2], s[3]));
    float e0 = __expf(s[0] - mx), e1 = __expf(s[1] - mx);
    float e2 = __expf(s[2] - mx), e3 = __expf(s[3] - mx);
    float inv = 1.0f / (e0 + e1 + e2 + e3);
    a0 = e0 * inv; a1 = e1 * inv; a2 = e2 * inv;  // a3 never needed
  }

  // 8 half2 slots per edge; 32 lanes handle 4 edges per iteration so one
  // wave-atomic touches few cache lines (8 lanes cover one edge's 32 B).
  const int pair = lane & 7;   // half2 slot: comps (2*pair, 2*pair+1)
  const int sub  = lane >> 3;  // which of the 4 in-flight edges
  int pa0, pr0, pa1, pr1;
  sel_comp(2 * pair, pa0, pr0);
  sel_comp(2 * pair + 1, pa1, pr1);

  for (int t2 = 0; t2 < valid_n; t2 += 4) {
    const int src = t2 + sub;
    float tx = __shfl(rx, src, 32);
    float ty = __shfl(ry, src, 32);
    float tz = __shfl(rz, src, 32);
    float b0 = __shfl(a0, src, 32);
    float b1 = __shfl(a1, src, 32);
    float b2 = __shfl(a2, src, 32);
    int   ct = __shfl(c,  src, 32);
    float A0 = (pa0 == 0) ? b0 : (pa0 == 1) ? b1 : (pa0 == 2) ? b2 : 1.0f;
    float R0 = (pr0 == 0) ? tx : (pr0 == 1) ? ty : (pr0 == 2) ? tz : 1.0f;
    float A1 = (pa1 == 0) ? b0 : (pa1 == 1) ? b1 : (pa1 == 2) ? b2 : 1.0f;
    float R1 = (pr1 == 0) ? tx : (pr1 == 1) ? ty : (pr1 == 2) ? tz : 1.0f;
    if (src < valid_n)
      pk_atomic_add(fsums + (size_t)ct * 16 + 2 * pair, A0 * R0, A1 * R1);
  }
}

__global__ __launch_bounds__(256) void node_kernel(
    const _Float16* __restrict__ fsums, const float* __restrict__ T,
    const float* __restrict__ bout, const float* __restrict__ gamma,
    const float* __restrict__ beta, float* __restrict__ out, int N) {
  const int tid = blockIdx.x * blockDim.x + threadIdx.x;
  const int node = tid >> 5;
  const int col = tid & 31;
  if (node >= N) return;

  // All 32 lanes of a node read the same 32 B (two dwordx4 broadcast loads)
  // instead of 16 ds_bpermute broadcasts.
  const f16x8* fp = (const f16x8*)(fsums + (size_t)node * 16);
  const f16x8 va = fp[0];
  const f16x8 vb = fp[1];
  float f[16];
#pragma unroll
  for (int j = 0; j < 8; ++j) {
    f[j] = (float)va[j];
    f[8 + j] = (float)vb[j];
  }
  const float invc = 1.0f / fmaxf(f[15], 1.0f);

  float acc = 0.f;
#pragma unroll
  for (int j = 0; j < 16; ++j) acc = fmaf(f[j], T[j * 32 + col], acc);
  acc = fmaf(acc, invc, bout[col]);

  float sx = acc, sx2 = acc * acc;
#pragma unroll
  for (int off = 16; off >= 1; off >>= 1) {
    sx += __shfl_xor(sx, off);
    sx2 += __shfl_xor(sx2, off);
  }
  const float mu = sx * (1.0f / 32.0f);
  const float var = sx2 * (1.0f / 32.0f) - mu * mu;
  const float inv = rsqrtf(var + LN_EPS);
  const float y = (acc - mu) * inv * gamma[col] + beta[col];
  const float o = y * (1.0f / (1.0f + __expf(-y)));  // SiLU
  out[(size_t)node * 32 + col] = o;
}

extern "C" void kernel_launch(void* const* d_in, const int* in_sizes, int n_in,
                              void* d_out, int out_size, void* d_ws, size_t ws_size,
                              hipStream_t stream) {
  const float* pos  = (const float*)d_in[0];
  const int*   ei   = (const int*)d_in[1];
  const float* Wq   = (const float*)d_in[2];
  const float* bq   = (const float*)d_in[3];
  const float* Wk   = (const float*)d_in[4];
  const float* bk   = (const float*)d_in[5];
  const float* Wv   = (const float*)d_in[6];
  const float* bv   = (const float*)d_in[7];
  const float* Wout = (const float*)d_in[8];
  const float* bout = (const float*)d_in[9];
  const float* gam  = (const float*)d_in[10];
  const float* bet  = (const float*)d_in[11];

  const int N = in_sizes[0] / 3;
  const int E = in_sizes[1] / 2;

  _Float16* fsums = (_Float16*)d_ws;                       // N*16 halves
  float* T = (float*)((char*)d_ws + (size_t)N * 32);       // 512 floats

  hipMemsetAsync(d_ws, 0, (size_t)N * 32, stream);

  const int edge_blocks = (E + 255) / 256;  // 8 groups of 32 edges per block
  edge_kernel<<<edge_blocks, 256, 0, stream>>>(pos, ei, E, Wq, bq, Wk, bk, Wv,
                                               bv, Wout, T, fsums);

  const int node_blocks = (int)(((size_t)N * 32 + 255) / 256);
  node_kernel<<<node_blocks, 256, 0, stream>>>(fsums, T, bout, gam, bet,
                                               (float*)d_out, N);

  (void)n_in; (void)out_size; (void)ws_size;
}

// Round 3
// 143.360 us; speedup vs baseline: 1.0963x; 1.0263x over previous
//
#include <hip/hip_runtime.h>
#include <hip/hip_fp16.h>

#define LN_EPS 1e-5f

typedef _Float16 f16x2 __attribute__((ext_vector_type(2)));
typedef _Float16 f16x8 __attribute__((ext_vector_type(8)));

__device__ __forceinline__ void pk_atomic_add_u32(_Float16* p, unsigned bits) {
  f16x2 v = __builtin_bit_cast(f16x2, bits);
#if __has_builtin(__builtin_amdgcn_flat_atomic_fadd_v2f16)
  __builtin_amdgcn_flat_atomic_fadd_v2f16((f16x2*)p, v);
#else
  unsafeAtomicAdd((__half2*)p, *(__half2*)&v);
#endif
}

__device__ __forceinline__ unsigned pack2(float a, float b) {
  f16x2 v;
  v.x = (_Float16)a;
  v.y = (_Float16)b;
  return __builtin_bit_cast(unsigned, v);
}

// ---------------------------------------------------------------------------
// Algebra: per-edge contribution to the (pre-mean) node feature is
//   contrib[col] = sum_h a_h (rel . M_h[col] + cv_h[col])
// linear in f = (a0,a1,a2, rx,ry,rz, a_h*rel_i for h<3, 1)  [16 dims]
// (sum_h a_h = 1 eliminates head 3). scatter-mean(contrib) = scatter-mean(f) @ T.
// f[15] = 1 doubles as the count. f accumulated in f16 via packed atomics.
//
// Round-3 structure change: the register->"8 lanes per edge" transpose that
// fed the atomics via 7 __shfl per iteration (56 DS ops/lane) now goes
// through LDS: each thread packs its edge's 8 half2 words, writes them
// slot-major (8 conflict-free ds_write_b32), barrier, then the atomic phase
// reads back in 8-lanes-per-edge layout (8 ds_read_b32, <=2-way conflict =
// free). Atomic cacheline grouping (8 edges x 8 slots per wave instruction)
// is preserved. This is also the ablation for "are we atomic-bound?":
// if edge time doesn't move, the atomic stream is the ceiling.
//
// ws layout: [0, N*16) _Float16 f-sum accumulators, then T (512 floats).
// ---------------------------------------------------------------------------

__global__ __launch_bounds__(256) void edge_kernel(
    const float* __restrict__ pos, const int* __restrict__ ei, int E,
    const float* __restrict__ Wq, const float* __restrict__ bq,
    const float* __restrict__ Wk, const float* __restrict__ bk,
    const float* __restrict__ Wv, const float* __restrict__ bv,
    const float* __restrict__ Wout, float* __restrict__ T,
    _Float16* __restrict__ fsums) {
  __shared__ float sW[1024];      // Wq[384] Wk[384] bq[128] bk[128]
  __shared__ float scoef[40];
  __shared__ float sM[4][3][32];
  __shared__ float sCv[4][32];
  __shared__ unsigned sF[8][264]; // slot-major packed f16x2, padded stride
  __shared__ int sC[256];

  const int t = threadIdx.x;
  const int lane64 = t & 63;
  const float scale = 0.17677669529663687f;  // 1/sqrt(32)

  // --- int64 layout probe, wave-local (no barrier): odd 32-bit words of the
  // first 8 indices are all zero iff buffer is little-endian int64.
  bool pz = true;
  if (lane64 < 8) pz = (ei[2 * lane64 + 1] == 0);
  const unsigned long long bz = __ballot(pz);
  const int i64 = (int)__builtin_amdgcn_readfirstlane(bz == ~0ull ? 1 : 0);

  // --- issue own-edge gathers immediately; they overlap the LDS phases.
  const int base = blockIdx.x * 256;
  const int vb = min(256, E - base);  // grid sized so vb >= 1
  const int e = base + t;

  int c = 0;
  float px0 = 0, px1 = 0, px2 = 0, pc0 = 0, pc1 = 0, pc2 = 0;
  if (t < vb) {
    int r;
    if (i64) {
      r = ((const int2*)ei)[(size_t)e].x;
      c = ((const int2*)ei)[(size_t)E + (size_t)e].x;
    } else {
      r = ei[e];
      c = ei[(size_t)E + e];
    }
    px0 = pos[r * 3 + 0]; px1 = pos[r * 3 + 1]; px2 = pos[r * 3 + 2];
    pc0 = pos[c * 3 + 0]; pc1 = pos[c * 3 + 1]; pc2 = pos[c * 3 + 2];
  }

  // --- stage Wq/Wk/bq/bk to LDS (coalesced, whole block)
  for (int i = t; i < 384; i += 256) {
    sW[i] = Wq[i];
    sW[384 + i] = Wk[i];
  }
  if (t < 128) {
    sW[768 + t] = bq[t];
    sW[896 + t] = bk[t];
  }
  __syncthreads();

  // --- coef from LDS (threads 0..39)
  if (t < 40) {
    const int h = t / 10, j = t % 10;
    float acc = 0.f;
#pragma unroll 4
    for (int d = 0; d < 32; ++d) {
      const int idx = h * 32 + d;
      float q0 = sW[idx], q1 = sW[128 + idx], q2 = sW[256 + idx];
      float k0 = sW[384 + idx], k1 = sW[512 + idx], k2 = sW[640 + idx];
      float bqv = sW[768 + idx], bkv = sW[896 + idx];
      float v;
      switch (j) {
        case 0: v = q0 * k0; break;
        case 1: v = q1 * k1; break;
        case 2: v = q2 * k2; break;
        case 3: v = q0 * k1 + q1 * k0; break;
        case 4: v = q0 * k2 + q2 * k0; break;
        case 5: v = q1 * k2 + q2 * k1; break;
        case 6: v = q0 * bkv + k0 * bqv; break;
        case 7: v = q1 * bkv + k1 * bqv; break;
        case 8: v = q2 * bkv + k2 * bqv; break;
        default: v = bqv * bkv; break;
      }
      acc += v;
    }
    scoef[t] = acc * scale;
  }

  // --- block 0 only: T factors, on threads 128..255 (parallel with coef)
  if (blockIdx.x == 0 && t >= 128) {
    const int h = (t - 128) >> 5, o = t & 31;
    float m0 = 0, m1 = 0, m2 = 0, cv = 0;
    for (int d = 0; d < 32; ++d) {
      const int j = h * 32 + d;
      const float w = Wout[j * 32 + o];
      m0 += Wv[j] * w;
      m1 += Wv[128 + j] * w;
      m2 += Wv[256 + j] * w;
      cv += bv[j] * w;
    }
    sM[h][0][o] = m0;
    sM[h][1][o] = m1;
    sM[h][2][o] = m2;
    sCv[h][o] = cv;
  }
  __syncthreads();

  if (blockIdx.x == 0) {
    for (int idx = t; idx < 512; idx += 256) {
      const int j = idx >> 5, col = idx & 31;
      float v;
      if (j < 3)        v = sCv[j][col] - sCv[3][col];
      else if (j < 6)   v = sM[3][j - 3][col];
      else if (j < 15)  { const int h = (j - 6) / 3, i = (j - 6) % 3; v = sM[h][i][col] - sM[3][i][col]; }
      else              v = sCv[3][col];
      T[idx] = v;
    }
  }

  // --- per-edge bulk compute: softmax weights, pack f into LDS
  if (t < vb) {
    const float rx = px0 - pc0;
    const float ry = px1 - pc1;
    const float rz = px2 - pc2;
    float s[4];
#pragma unroll
    for (int h = 0; h < 4; ++h) {
      const float* cf = scoef + h * 10;
      s[h] = cf[9] + rx * cf[6] + ry * cf[7] + rz * cf[8] + rx * rx * cf[0] +
             ry * ry * cf[1] + rz * rz * cf[2] + rx * ry * cf[3] +
             rx * rz * cf[4] + ry * rz * cf[5];
    }
    const float mx = fmaxf(fmaxf(s[0], s[1]), fmaxf(s[2], s[3]));
    const float e0 = __expf(s[0] - mx), e1 = __expf(s[1] - mx);
    const float e2 = __expf(s[2] - mx), e3 = __expf(s[3] - mx);
    const float inv = 1.0f / (e0 + e1 + e2 + e3);
    const float a0 = e0 * inv, a1 = e1 * inv, a2 = e2 * inv;  // a3 not needed

    sC[t] = c;
    sF[0][t] = pack2(a0, a1);
    sF[1][t] = pack2(a2, rx);
    sF[2][t] = pack2(ry, rz);
    sF[3][t] = pack2(a0 * rx, a0 * ry);
    sF[4][t] = pack2(a0 * rz, a1 * rx);
    sF[5][t] = pack2(a1 * ry, a1 * rz);
    sF[6][t] = pack2(a2 * rx, a2 * ry);
    sF[7][t] = pack2(a2 * rz, 1.0f);
  }
  __syncthreads();

  // --- atomic phase: 8 lanes per edge, 8 edges per wave-instruction so one
  // wave-atomic touches few cachelines.
  const int w = t >> 6;
  const int slot = lane64 & 7;
  const int esub = lane64 >> 3;
#pragma unroll
  for (int i = 0; i < 8; ++i) {
    const int g = w * 64 + i * 8 + esub;
    if (g < vb) {
      const int ct = sC[g];
      const unsigned val = sF[slot][g];
      pk_atomic_add_u32(fsums + (size_t)ct * 16 + 2 * slot, val);
    }
  }
}

__global__ __launch_bounds__(256) void node_kernel(
    const _Float16* __restrict__ fsums, const float* __restrict__ T,
    const float* __restrict__ bout, const float* __restrict__ gamma,
    const float* __restrict__ beta, float* __restrict__ out, int N) {
  const int tid = blockIdx.x * blockDim.x + threadIdx.x;
  const int node = tid >> 5;
  const int col = tid & 31;
  if (node >= N) return;

  // All 32 lanes of a node read the same 32 B (two dwordx4 broadcast loads).
  const f16x8* fp = (const f16x8*)(fsums + (size_t)node * 16);
  const f16x8 va = fp[0];
  const f16x8 vb = fp[1];
  float f[16];
#pragma unroll
  for (int j = 0; j < 8; ++j) {
    f[j] = (float)va[j];
    f[8 + j] = (float)vb[j];
  }
  const float invc = 1.0f / fmaxf(f[15], 1.0f);

  float acc = 0.f;
#pragma unroll
  for (int j = 0; j < 16; ++j) acc = fmaf(f[j], T[j * 32 + col], acc);
  acc = fmaf(acc, invc, bout[col]);

  float sx = acc, sx2 = acc * acc;
#pragma unroll
  for (int off = 16; off >= 1; off >>= 1) {
    sx += __shfl_xor(sx, off);
    sx2 += __shfl_xor(sx2, off);
  }
  const float mu = sx * (1.0f / 32.0f);
  const float var = sx2 * (1.0f / 32.0f) - mu * mu;
  const float inv = rsqrtf(var + LN_EPS);
  const float y = (acc - mu) * inv * gamma[col] + beta[col];
  const float o = y * (1.0f / (1.0f + __expf(-y)));  // SiLU
  out[(size_t)node * 32 + col] = o;
}

extern "C" void kernel_launch(void* const* d_in, const int* in_sizes, int n_in,
                              void* d_out, int out_size, void* d_ws, size_t ws_size,
                              hipStream_t stream) {
  const float* pos  = (const float*)d_in[0];
  const int*   ei   = (const int*)d_in[1];
  const float* Wq   = (const float*)d_in[2];
  const float* bq   = (const float*)d_in[3];
  const float* Wk   = (const float*)d_in[4];
  const float* bk   = (const float*)d_in[5];
  const float* Wv   = (const float*)d_in[6];
  const float* bv   = (const float*)d_in[7];
  const float* Wout = (const float*)d_in[8];
  const float* bout = (const float*)d_in[9];
  const float* gam  = (const float*)d_in[10];
  const float* bet  = (const float*)d_in[11];

  const int N = in_sizes[0] / 3;
  const int E = in_sizes[1] / 2;

  _Float16* fsums = (_Float16*)d_ws;                       // N*16 halves
  float* T = (float*)((char*)d_ws + (size_t)N * 32);       // 512 floats

  hipMemsetAsync(d_ws, 0, (size_t)N * 32, stream);

  const int edge_blocks = (E + 255) / 256;  // one edge per thread
  edge_kernel<<<edge_blocks, 256, 0, stream>>>(pos, ei, E, Wq, bq, Wk, bk, Wv,
                                               bv, Wout, T, fsums);

  const int node_blocks = (int)(((size_t)N * 32 + 255) / 256);
  node_kernel<<<node_blocks, 256, 0, stream>>>(fsums, T, bout, gam, bet,
                                               (float*)d_out, N);

  (void)n_in; (void)out_size; (void)ws_size;
}